// Round 14
// baseline (82.843 us; speedup 1.0000x reference)
//
#include <hip/hip_runtime.h>

typedef unsigned long long u64;

#define NIMG 4
#define H 256
#define W 256
#define NPIX (H*W)           // 65536 per image
#define NTOT (NIMG*NPIX)     // 262144
#define WPR 4                // u64 words per row (256 bits)
#define WPI (H*WPR)          // 1024 words per image
#define WPB (NIMG*WPI)       // 4096 words per branch
#define XT 8                 // columns per tile block (both branches)
#define NSKEL 8              // skeleton blocks (1 per branch-image)
#define NTILE 128            // tile blocks: 4 img x 32 col-tiles
#define NB2 (NSKEL+NTILE)    // 136 blocks: all co-resident (<=256 CUs)

// Control-state layout: ONE counter per 128-B line (r10/r11-proven).
#define CFLAG(bi)  ((bi)*32)        // skel flags, bi=0..7
#define CDONE      256              // done counter
#define CBAR(img)  (288+(img)*32)   // per-image rmm sub-barriers (32 arrivals)
#define CMASK(img) (416+(img)*32)   // r14: per-image mask-ready (32 arrivals)
// Data atomics, one entry per 128-B line (r11-proven, -7us):
#define RMM(i)     ((i)*32)
#define SUM(i)     ((i)*16)
// r12 LESSON: never per-block ACQUIRE (cache invalidates under live peers).
// Release RMWs are proven cheap (128 CBAR releases in the champion).
// r14: rmm min stored as atomicMax(~bits) (r7-proven) so memset-0 is the
// identity -> init kernel not needed.

// ---------------------------------------------------------------------------
// Bit-parallel morphology helpers. Bit b of word k = pixel x = 64k+b.
// Erode = AND over cross; OOB=1.  Dilate = OR over 3x3 box; OOB=0.
// ---------------------------------------------------------------------------
__device__ __forceinline__ void erode_from(const u64 S[][WPR], int y, u64 out[WPR]) {
  u64 c[WPR], up[WPR], dn[WPR];
#pragma unroll
  for (int k = 0; k < WPR; ++k) {
    c[k]  = S[y][k];
    up[k] = (y > 0)     ? S[y-1][k] : ~0ULL;
    dn[k] = (y < H-1)   ? S[y+1][k] : ~0ULL;
  }
#pragma unroll
  for (int k = 0; k < WPR; ++k) {
    u64 l = (c[k] << 1) | ((k > 0)     ? (c[k-1] >> 63) : 1ULL);
    u64 r = (c[k] >> 1) | ((k < WPR-1) ? (c[k+1] << 63) : 0x8000000000000000ULL);
    out[k] = c[k] & up[k] & dn[k] & l & r;
  }
}

__device__ __forceinline__ void dilate_from(const u64 S[][WPR], int y, u64 out[WPR]) {
  u64 v[WPR];
#pragma unroll
  for (int k = 0; k < WPR; ++k) {
    u64 a = S[y][k];
    if (y > 0)   a |= S[y-1][k];
    if (y < H-1) a |= S[y+1][k];
    v[k] = a;
  }
#pragma unroll
  for (int k = 0; k < WPR; ++k) {
    u64 l = (v[k] << 1) | ((k > 0)     ? (v[k-1] >> 63) : 0ULL);
    u64 r = (v[k] >> 1) | ((k < WPR-1) ? (v[k+1] << 63) : 0ULL);
    out[k] = v[k] | l | r;
  }
}

// EDT pass: phase 1 (horizontal clz/ctz; mask rows via sc1 loads — masks are
// produced intra-kernel at the LLC, same cost as the old post-boundary LLC
// reads) -> col2; phase 2 (vertical early-exit envelope) -> DIST[8] regs.
// SAVE_MASK stashes the tile's true-mask word for the q-phase.
#define EDT_PASS(WBASE, DIST, SAVE_MASK)                                       \
  {                                                                            \
    int y = t;                                                                 \
    const u64* row = mask_bits + (WBASE) + y*WPR;                              \
    u64 z[WPR];                                                                \
    _Pragma("unroll")                                                          \
    for (int k = 0; k < WPR; ++k) {                                            \
      u64 m = __hip_atomic_load(&row[k], __ATOMIC_RELAXED,                     \
                                __HIP_MEMORY_SCOPE_AGENT);                     \
      if (SAVE_MASK && k == kx) msk_row[y] = m;                                \
      z[k] = ~m;                        /* background bits */                  \
    }                                                                          \
    _Pragma("unroll")                                                          \
    for (int xx = 0; xx < XT; ++xx) {                                          \
      int x = x0 + xx;                                                         \
      int bx = x & 63;                                                         \
      int ld = 512;                                                            \
      {                                                                        \
        u64 w = z[kx] & ((bx == 63) ? ~0ULL : ((1ULL << (bx+1)) - 1ULL));      \
        for (int k = kx; ; ) {                                                 \
          if (w) { int pos = 63 - __builtin_clzll(w) + (k << 6); ld = x - pos; break; } \
          if (--k < 0) break;                                                  \
          w = z[k];                                                            \
        }                                                                      \
      }                                                                        \
      int rd = 512;                                                            \
      {                                                                        \
        u64 w = z[kx] & (~0ULL << bx);                                         \
        for (int k = kx; ; ) {                                                 \
          if (w) { int pos = __builtin_ctzll(w) + (k << 6); rd = pos - x; break; } \
          if (++k > WPR-1) break;                                              \
          w = z[k];                                                            \
        }                                                                      \
      }                                                                        \
      int g = min(ld, rd);                                                     \
      col2[y][xx] = (float)(g * g);                                            \
    }                                                                          \
  }                                                                            \
  __syncthreads();                                                             \
  _Pragma("unroll")                                                            \
  for (int j = 0; j < 8; ++j) {                                                \
    int y = yg * 8 + j;                                                        \
    float best = col2[y][xq];                                                  \
    for (int k = 1; k < H; ++k) {                                              \
      float k2 = (float)(k * k);                                               \
      if (k2 >= best) break;           /* no farther candidate improves */     \
      int ym = y - k, yd = y + k;                                              \
      if (ym >= 0) best = fminf(best, col2[ym][xq] + k2);                      \
      if (yd < H)  best = fminf(best, col2[yd][xq] + k2);                      \
    }                                                                          \
    (DIST)[j] = sqrtf(best);                                                   \
  }                                                                            \
  __syncthreads();

// ---------------------------------------------------------------------------
// SINGLE compute kernel (prep merged in). 136 blocks x 256 threads.
//  tile blocks (8..135): build OWN 2048-px slice of BOTH branch masks —
//    ONE iteration/thread (32 B coalesced loads, r8 byte-predicate, LDS
//    stage, 64 sc1 u64 stores; NOT r2's 256-iter ballot loop, NOT r7/r8's
//    whole-image redundancy) -> release-RMW per-image CMASK barrier (the
//    CBAR pattern, proven at 128 releases) -> EDT both branches -> skel-flag
//    wait + sc1 staging -> rmm (max=bits, min=~bits) + CBAR -> q-phase ->
//    relaxed sums + threadfence + CDONE, last block finalizes (r13 tail).
//  skel blocks (0..7): wait CMASK, sc1-load mask, soft_skel (r4-proven),
//    threadfence release + flag, exit.
// Init: 5 KB hipMemsetAsync (graph-safe, r7-proven); all encodings have
// 0 as the atomic identity.
// ---------------------------------------------------------------------------
__global__ void __launch_bounds__(256, 1) fused_kernel(
    const float* __restrict__ y_pred, const int* __restrict__ y_true,
    u64* __restrict__ mask_bits, u64* __restrict__ skel_bits,
    unsigned* __restrict__ rmm_u, double* __restrict__ sums,
    unsigned* __restrict__ cnts, float* __restrict__ out) {
  __shared__ u64 SA[H][WPR];
  __shared__ u64 SB[H][WPR];
  __shared__ float col2[H][XT + 1];
  __shared__ u64 srow_t[H];
  __shared__ u64 srow_p[H];
  __shared__ u64 msk_row[H];
  __shared__ float redf[4][4];
  __shared__ unsigned smm[4];
  __shared__ unsigned char mbuf[2][256];   // mask-build staging (512 B)
  int t = threadIdx.x;

  if (blockIdx.x < NSKEL) {
    // ---- skel block: wait for its image's mask, then soft_skel ----
    int bi  = blockIdx.x;                 // branch*4+img
    int img = bi & 3;
    if (t == 0) {
      while (__hip_atomic_load(&cnts[CMASK(img)], __ATOMIC_RELAXED,
                               __HIP_MEMORY_SCOPE_AGENT) < 32u)
        __builtin_amdgcn_s_sleep(8);
    }
    __syncthreads();
    int y = t;
    int base = bi * WPI;
    u64 a[WPR], cur[WPR], e[WPR], d[WPR], sk[WPR];
#pragma unroll
    for (int k = 0; k < WPR; ++k) {
      a[k] = __hip_atomic_load(&mask_bits[base + y*WPR + k],
                               __ATOMIC_RELAXED, __HIP_MEMORY_SCOPE_AGENT);
      SA[y][k] = a[k];
    }
    __syncthreads();
    erode_from(SA, y, e);                 // E1 = erode(a)
#pragma unroll
    for (int k = 0; k < WPR; ++k) SB[y][k] = e[k];
    __syncthreads();                      // SB visible; all SA reads complete
    dilate_from(SB, y, d);                // open(a)
#pragma unroll
    for (int k = 0; k < WPR; ++k) { sk[k] = a[k] & ~d[k]; cur[k] = e[k]; }
    u64 (*P)[WPR] = SB;                   // current erosion level E_k
    u64 (*Q)[WPR] = SA;                   // dead buffer
    for (int it = 0; it < 10; ++it) {     // levels 1..10
      erode_from(P, y, e);                // E_{k+1}
#pragma unroll
      for (int k = 0; k < WPR; ++k) Q[y][k] = e[k];   // overwrite dead data
      __syncthreads();                    // publish Q; P reads all done
      dilate_from(Q, y, d);               // open(E_k)
#pragma unroll
      for (int k = 0; k < WPR; ++k) { sk[k] |= cur[k] & ~d[k]; cur[k] = e[k]; }
      u64 (*T)[WPR] = P; P = Q; Q = T;
    }
#pragma unroll
    for (int k = 0; k < WPR; ++k) skel_bits[base + y*WPR + k] = sk[k];
    __syncthreads();                      // all stores issued + vmcnt drained
    if (t == 0) {
      __threadfence();                    // release: writeback XCD L2 (8 total)
      atomicAdd(&cnts[CFLAG(bi)], 1u);    // per-(branch,image) flag, own line
    }
    return;
  }

  // ===================== tile blocks (8..135) =====================
  int tb  = blockIdx.x - NSKEL;          // 0..127
  int img = tb >> 5;                     // 0..3
  int xt  = tb & 31;                     // 0..31
  int x0  = xt * XT;
  int kx  = x0 >> 6;                     // tile's 8 columns share this word
  int sh0 = x0 & 63;                     // <= 56
  int xq  = t & (XT - 1);                // phase-2/q column 0..7
  int yg  = t >> 3;                      // phase-2/q row group 0..31

  // ---- build OWN 2048-px mask slice, both branches (rows xt*8..xt*8+7) ----
  {
    int px0 = img * NPIX + xt * 2048;    // this block's pixel slice
    const int4*   ti = (const int4*)(y_true + px0 + t * 8);
    const float4* pf = (const float4*)(y_pred + px0 + t * 8);
    int4   a0 = ti[0], a1 = ti[1];
    float4 f0 = pf[0], f1 = pf[1];
    unsigned bt = (unsigned)(a0.x > 0)        | ((unsigned)(a0.y > 0) << 1)
                | ((unsigned)(a0.z > 0) << 2) | ((unsigned)(a0.w > 0) << 3)
                | ((unsigned)(a1.x > 0) << 4) | ((unsigned)(a1.y > 0) << 5)
                | ((unsigned)(a1.z > 0) << 6) | ((unsigned)(a1.w > 0) << 7);
    unsigned bp = (unsigned)(f0.x > 0.0f)        | ((unsigned)(f0.y > 0.0f) << 1)
                | ((unsigned)(f0.z > 0.0f) << 2) | ((unsigned)(f0.w > 0.0f) << 3)
                | ((unsigned)(f1.x > 0.0f) << 4) | ((unsigned)(f1.y > 0.0f) << 5)
                | ((unsigned)(f1.z > 0.0f) << 6) | ((unsigned)(f1.w > 0.0f) << 7);
    mbuf[0][t] = (unsigned char)bt;      // x>0 == pp>0.5 exactly (monotone)
    mbuf[1][t] = (unsigned char)bp;
  }
  __syncthreads();
  if (t < 64) {                          // 64 wide sc1 u64 stores -> LLC
    u64 w = ((const u64*)mbuf)[t];       // words 0..31 true, 32..63 pred
    int wbase = img * WPI + xt * 32;
    u64* dst = (t < 32) ? &mask_bits[wbase + t]
                        : &mask_bits[WPB + wbase + (t - 32)];
    __hip_atomic_store(dst, w, __ATOMIC_RELAXED, __HIP_MEMORY_SCOPE_AGENT);
  }
  __syncthreads();                       // vmcnt drain: stores at LLC
  if (t == 0) {
    // release RMW (CBAR-proven pattern) publishes; then wait for all 32
    __hip_atomic_fetch_add(&cnts[CMASK(img)], 1u, __ATOMIC_RELEASE,
                           __HIP_MEMORY_SCOPE_AGENT);
    while (__hip_atomic_load(&cnts[CMASK(img)], __ATOMIC_RELAXED,
                             __HIP_MEMORY_SCOPE_AGENT) < 32u)
      __builtin_amdgcn_s_sleep(8);
  }
  __syncthreads();

  float dist_t[8], dist_p[8];
  EDT_PASS(img*WPI,     dist_t, 1)       // true branch (saves mask word)
  EDT_PASS((4+img)*WPI, dist_p, 0)       // pred branch

  // --- wait for BOTH skel flags: ONE combined poll loop, own lines ---
  if (t == 0) {
    while (__hip_atomic_load(&cnts[CFLAG(img)], __ATOMIC_RELAXED,
                             __HIP_MEMORY_SCOPE_AGENT) == 0u ||
           __hip_atomic_load(&cnts[CFLAG(4+img)], __ATOMIC_RELAXED,
                             __HIP_MEMORY_SCOPE_AGENT) == 0u)
      __builtin_amdgcn_s_sleep(8);
  }
  __syncthreads();
  // stage skel words for this tile (sc1: bypass stale L2, LLC-coherent)
  srow_t[t] = __hip_atomic_load(&skel_bits[img*WPI + t*WPR + kx],
                                __ATOMIC_RELAXED, __HIP_MEMORY_SCOPE_AGENT);
  srow_p[t] = __hip_atomic_load(&skel_bits[(4+img)*WPI + t*WPR + kx],
                                __ATOMIC_RELAXED, __HIP_MEMORY_SCOPE_AGENT);
  __syncthreads();

  // --- fused rmax/rmin for BOTH branches (regs + LDS only) ---
  float vmax_t = 0.0f, vmin_t = 3.0e38f, vmax_p = 0.0f, vmin_p = 3.0e38f;
#pragma unroll
  for (int j = 0; j < 8; ++j) {
    int y = yg * 8 + j;
    int sb_t = (int)((srow_t[y] >> (sh0 + xq)) & 1ULL);
    int sb_p = (int)((srow_p[y] >> (sh0 + xq)) & 1ULL);
    float srt = sb_t ? dist_t[j] : 0.0f;  // skel_radius, true branch
    float srp = sb_p ? dist_p[j] : 0.0f;  // skel_radius, pred branch
    vmax_t = fmaxf(vmax_t, srt); vmin_t = fminf(vmin_t, srt);
    vmax_p = fmaxf(vmax_p, srp); vmin_p = fminf(vmin_p, srp);
  }
  for (int o = 32; o > 0; o >>= 1) {
    vmax_t = fmaxf(vmax_t, __shfl_down(vmax_t, o, 64));
    vmin_t = fminf(vmin_t, __shfl_down(vmin_t, o, 64));
    vmax_p = fmaxf(vmax_p, __shfl_down(vmax_p, o, 64));
    vmin_p = fminf(vmin_p, __shfl_down(vmin_p, o, 64));
  }
  int wave = t >> 6, lane = t & 63;
  if (lane == 0) { redf[wave][0]=vmax_t; redf[wave][1]=vmin_t;
                   redf[wave][2]=vmax_p; redf[wave][3]=vmin_p; }
  __syncthreads();
  if (t == 0) {
    float mxt=redf[0][0], mnt=redf[0][1], mxp=redf[0][2], mnp=redf[0][3];
    for (int wv = 1; wv < 4; ++wv) {
      mxt = fmaxf(mxt, redf[wv][0]); mnt = fminf(mnt, redf[wv][1]);
      mxp = fmaxf(mxp, redf[wv][2]); mnp = fminf(mnp, redf[wv][3]);
    }
    // padded rmm; max stored as bits, min as ~bits (0 = identity for both)
    atomicMax(&rmm_u[RMM(img*2 + 0)],     __float_as_uint(mxt));
    atomicMax(&rmm_u[RMM(img*2 + 1)],     ~__float_as_uint(mnt));
    atomicMax(&rmm_u[RMM((4+img)*2 + 0)], __float_as_uint(mxp));
    atomicMax(&rmm_u[RMM((4+img)*2 + 1)], ~__float_as_uint(mnp));
    // per-image sub-barrier (32 arrivals), own line: release RMW orders
    // the rmm atomics (all at LLC — nothing dirty in L2)
    __hip_atomic_fetch_add(&cnts[CBAR(img)], 1u, __ATOMIC_RELEASE,
                           __HIP_MEMORY_SCOPE_AGENT);
    while (__hip_atomic_load(&cnts[CBAR(img)], __ATOMIC_RELAXED,
                             __HIP_MEMORY_SCOPE_AGENT) < 32u)
      __builtin_amdgcn_s_sleep(8);
  }
  __syncthreads();
  if (t < 4) {
    int idx = (t < 2) ? (img*2 + t) : ((4+img)*2 + (t-2));
    smm[t] = __hip_atomic_load(&rmm_u[RMM(idx)], __ATOMIC_RELAXED,
                               __HIP_MEMORY_SCOPE_AGENT);
  }
  __syncthreads();
  float rmax_t = fmaxf(__uint_as_float( smm[0]), 1.0f);
  float rmin_t = fmaxf(__uint_as_float(~smm[1]), 1.0f);
  float rmax_p = fmaxf(__uint_as_float( smm[2]), 1.0f);
  float rmin_p = fmaxf(__uint_as_float(~smm[3]), 1.0f);

  // --- q-phase over this block's OWN 2048 pixels (dist in regs) ---
  float q1 = 0.f, q2 = 0.f, q3 = 0.f, q4 = 0.f;
#pragma unroll
  for (int j = 0; j < 8; ++j) {
    int y = yg * 8 + j;
    float xv = y_pred[img*NPIX + y*W + x0 + xq];
    float p = 1.0f / (1.0f + expf(-xv));
    float ppv = 1.0f / (1.0f + expf(-(2.0f * p - 1.0f)));  // exact ref expr
    int b = sh0 + xq;
    int m_t  = (int)((msk_row[y] >> b) & 1ULL);
    int s_t  = (int)((srow_t[y] >> b) & 1ULL);
    int s_pb = (int)((srow_p[y] >> b) & 1ULL);
    // --- true branch (binary) ---
    float distances_t = m_t ? dist_t[j] : 0.0f;
    float skelrad_t   = s_t ? distances_t : 0.0f;
    float dmn_t = fminf(distances_t, rmax_t) / rmax_t;
    float srn_t = skelrad_t / rmax_t;
    float In_t  = s_t ? (rmax_t - skelrad_t + rmin_t) / rmax_t : 0.0f;
    float q_vl   = m_t ? dmn_t : 0.0f;
    float q_slvl = m_t ? srn_t : 0.0f;
    float q_sl   = s_t ? In_t  : 0.0f;
    // --- pred branch (probabilistic) ---
    float skel_in_p = s_pb ? ppv : 0.0f;      // skel_pred_prob
    bool msk_p = ppv > 0.5f;
    bool sk_p  = skel_in_p > 0.5f;
    float distances_p = msk_p ? dist_p[j] : 0.0f;
    float skelrad_p   = sk_p ? distances_p : 0.0f;
    float dmn_p = fminf(distances_p, rmax_p) / rmax_p;
    float srn_p = skelrad_p / rmax_p;
    float In_p  = sk_p ? (rmax_p - skelrad_p + rmin_p) / rmax_p : 0.0f;
    float q_vp   = dmn_p * ppv;
    float q_spvp = srn_p * ppv;
    float q_sp   = In_p * skel_in_p;
    q1 += q_sp * q_vl;
    q2 += (q_spvp != 0.0f && q_slvl == 0.0f) ? q_spvp * q_sp : q_slvl * q_sp;
    q3 += q_sl * q_vp;
    q4 += (q_slvl != 0.0f && q_spvp == 0.0f) ? q_slvl * q_sl : q_spvp * q_sl;
  }
  for (int o = 32; o > 0; o >>= 1) {
    q1 += __shfl_down(q1, o, 64);
    q2 += __shfl_down(q2, o, 64);
    q3 += __shfl_down(q3, o, 64);
    q4 += __shfl_down(q4, o, 64);
  }
  if (lane == 0) { redf[wave][0]=q1; redf[wave][1]=q2; redf[wave][2]=q3; redf[wave][3]=q4; }
  __syncthreads();
  if (t == 0) {
    float a0=0,a1=0,a2=0,a3=0;
    for (int wv = 0; wv < 4; ++wv) {
      a0 += redf[wv][0]; a1 += redf[wv][1]; a2 += redf[wv][2]; a3 += redf[wv][3];
    }
    // padded sums (r11); relaxed adds + ONE release fence (r12 lesson)
    atomicAdd(&sums[SUM(0)], (double)a0);
    atomicAdd(&sums[SUM(1)], (double)a1);
    atomicAdd(&sums[SUM(2)], (double)a2);
    atomicAdd(&sums[SUM(3)], (double)a3);
    __threadfence();                    // release-only: writeback, NO invalidate
    unsigned c = atomicAdd(&cnts[CDONE], 1u);
    if (c == NTILE - 1) {               // last block finalizes (device-scope
      double s0 = atomicAdd(&sums[SUM(0)], 0.0);  // atomic loads for coherence)
      double s1 = atomicAdd(&sums[SUM(1)], 0.0);
      double s2 = atomicAdd(&sums[SUM(2)], 0.0);
      double s3 = atomicAdd(&sums[SUM(3)], 0.0);
      double wp  = (s0 + 1.0) / (s1 + 1.0);
      double wsn = (s2 + 1.0) / (s3 + 1.0);
      out[0] = (float)(1.0 - 2.0 * (wp * wsn) / (wp + wsn));
    }
  }
}

extern "C" void kernel_launch(void* const* d_in, const int* in_sizes, int n_in,
                              void* d_out, int out_size, void* d_ws, size_t ws_size,
                              hipStream_t stream) {
  (void)in_sizes; (void)n_in; (void)out_size; (void)ws_size;
  const float* y_pred = (const float*)d_in[0];
  const int*   y_true = (const int*)d_in[1];
  float* out = (float*)d_out;
  char* ws = (char*)d_ws;

  // workspace layout (bytes) — ALL hot atomics on private 128-B lines
  u64*   mask_bits = (u64*)  (ws + 0);          // 8192 u64 (65,536 B)
  u64*   skel_bits = (u64*)  (ws + 65536);      // 8192 u64 (65,536 B)
  unsigned* rmm_u  = (unsigned*)(ws + 131072);  // 16 entries x 128 B (2048 B)
  double* sums     = (double*)(ws + 133120);    // 4 entries x 128 B (512 B)
  unsigned* cnts   = (unsigned*)(ws + 133632);  // 640 u32 padded (2560 B)

  // zero-init all control state (graph-safe, r7-proven; every atomic
  // encoding has 0 as its identity)
  hipMemsetAsync(ws + 131072, 0, 5120, stream);
  fused_kernel<<<NB2, 256, 0, stream>>>(y_pred, y_true, mask_bits, skel_bits,
                                        rmm_u, sums, cnts, out);
}

// Round 15
// 80.401 us; speedup vs baseline: 1.0304x; 1.0304x over previous
//
#include <hip/hip_runtime.h>

typedef unsigned long long u64;

#define NIMG 4
#define H 256
#define W 256
#define NPIX (H*W)           // 65536 per image
#define NTOT (NIMG*NPIX)     // 262144
#define WPR 4                // u64 words per row (256 bits)
#define WPI (H*WPR)          // 1024 words per image
#define WPB (NIMG*WPI)       // 4096 words per branch
#define XT 8                 // columns per tile block (both branches)
#define NSKEL 8              // skeleton blocks (1 per branch-image)
#define NTILE 128            // tile blocks: 4 img x 32 col-tiles
#define NB2 (NSKEL+NTILE)    // 136 blocks: all co-resident (<=256 CUs)

// Control-state layout: ONE counter per 128-B line (r10-proven: packed
// counters => LLC RMWs serialize behind 128 blocks' polls).
#define CFLAG(bi)  ((bi)*32)        // skel flags, bi=0..7 -> words 0..224
#define CDONE      256              // done counter
#define CBAR(img)  (288+(img)*32)   // per-image sub-barriers -> 288..384
// r11-proven: DATA atomics padded the same way — rmm entry i at word i*32
// (16 lines), sum i at double i*16 (4 lines). This was -7us.
// r12 LESSON: ACQ_REL RMWs per block = per-block cache INVALIDATES that
// evict y_pred from L2 under still-running peers (+5us). Relaxed + ONE
// release threadfence only.
// r14 LESSON: sc1 loads in a HOT loop (EDT mask reads) bypass L1/L2 ->
// LLC latency storm (+35us on the fused kernel); and in-kernel mask
// production serializes build->skel->EDT. The prep kernel boundary buys
// cached mask reads + skel starting at t=0 — keep the 2-kernel form.
#define RMM(i)     ((i)*32)
#define SUM(i)     ((i)*16)

// ---------------------------------------------------------------------------
// Bit-parallel morphology helpers. Bit b of word k = pixel x = 64k+b.
// Erode = AND over cross; OOB=1.  Dilate = OR over 3x3 box; OOB=0.
// ---------------------------------------------------------------------------
__device__ __forceinline__ void erode_from(const u64 S[][WPR], int y, u64 out[WPR]) {
  u64 c[WPR], up[WPR], dn[WPR];
#pragma unroll
  for (int k = 0; k < WPR; ++k) {
    c[k]  = S[y][k];
    up[k] = (y > 0)     ? S[y-1][k] : ~0ULL;
    dn[k] = (y < H-1)   ? S[y+1][k] : ~0ULL;
  }
#pragma unroll
  for (int k = 0; k < WPR; ++k) {
    u64 l = (c[k] << 1) | ((k > 0)     ? (c[k-1] >> 63) : 1ULL);
    u64 r = (c[k] >> 1) | ((k < WPR-1) ? (c[k+1] << 63) : 0x8000000000000000ULL);
    out[k] = c[k] & up[k] & dn[k] & l & r;
  }
}

__device__ __forceinline__ void dilate_from(const u64 S[][WPR], int y, u64 out[WPR]) {
  u64 v[WPR];
#pragma unroll
  for (int k = 0; k < WPR; ++k) {
    u64 a = S[y][k];
    if (y > 0)   a |= S[y-1][k];
    if (y < H-1) a |= S[y+1][k];
    v[k] = a;
  }
#pragma unroll
  for (int k = 0; k < WPR; ++k) {
    u64 l = (v[k] << 1) | ((k > 0)     ? (v[k-1] >> 63) : 0ULL);
    u64 r = (v[k] >> 1) | ((k < WPR-1) ? (v[k+1] << 63) : 0ULL);
    out[k] = v[k] | l | r;
  }
}

// ---------------------------------------------------------------------------
// K1: prep — 1 px/thread, NO loop (proven). Pred ballot on x>0 directly
// (== q>0.5 exactly: q = sigmoid(2*sigmoid(x)-1) is monotone in x with
// q(0)=0.5; bit-exactness proven by r7/r8/r12/r13 passes) — no expf.
// Block 0 inits padded rmm/sums/cnts a full boundary before any use.
// ---------------------------------------------------------------------------
__global__ void __launch_bounds__(256) prep_kernel(
    const float* __restrict__ y_pred, const int* __restrict__ y_true,
    u64* __restrict__ mask_bits, unsigned* __restrict__ rmm_u,
    double* __restrict__ sums, unsigned* __restrict__ cnts) {
  if (blockIdx.x == 0) {
    if (threadIdx.x < 16) rmm_u[RMM(threadIdx.x)] = (threadIdx.x & 1) ? 0x7F800000u : 0u; // min:+inf, max:0
    else if (threadIdx.x < 20) sums[SUM(threadIdx.x - 16)] = 0.0;
    cnts[threadIdx.x] = 0u;              // zero the whole padded region
    cnts[256 + threadIdx.x] = 0u;
  }
  int i = blockIdx.x * 256 + threadIdx.x;
  float x = y_pred[i];
  u64 bt = __ballot(y_true[i] > 0);
  u64 bp = __ballot(x > 0.0f);       // == (pp > 0.5), no expf needed
  if ((threadIdx.x & 63) == 0) {
    mask_bits[i >> 6] = bt;          // branch 0: true mask
    mask_bits[WPB + (i >> 6)] = bp;  // branch 1: pred hard mask
  }
}

// EDT pass: phase 1 (horizontal clz/ctz over global mask row, L2-hot 8 KB)
// -> col2; phase 2 (vertical early-exit envelope) -> DIST[8] registers.
// SAVE_MASK stashes the tile's true-mask word for the q-phase.
#define EDT_PASS(MROW, DIST, SAVE_MASK)                                        \
  {                                                                            \
    int y = t;                                                                 \
    const u64* row = (MROW) + y*WPR;                                           \
    u64 z[WPR];                                                                \
    _Pragma("unroll")                                                          \
    for (int k = 0; k < WPR; ++k) z[k] = ~row[k];   /* background bits */      \
    if (SAVE_MASK) msk_row[y] = row[kx];                                       \
    _Pragma("unroll")                                                          \
    for (int xx = 0; xx < XT; ++xx) {                                          \
      int x = x0 + xx;                                                         \
      int bx = x & 63;                                                         \
      int ld = 512;                                                            \
      {                                                                        \
        u64 w = z[kx] & ((bx == 63) ? ~0ULL : ((1ULL << (bx+1)) - 1ULL));      \
        for (int k = kx; ; ) {                                                 \
          if (w) { int pos = 63 - __builtin_clzll(w) + (k << 6); ld = x - pos; break; } \
          if (--k < 0) break;                                                  \
          w = z[k];                                                            \
        }                                                                      \
      }                                                                        \
      int rd = 512;                                                            \
      {                                                                        \
        u64 w = z[kx] & (~0ULL << bx);                                         \
        for (int k = kx; ; ) {                                                 \
          if (w) { int pos = __builtin_ctzll(w) + (k << 6); rd = pos - x; break; } \
          if (++k > WPR-1) break;                                              \
          w = z[k];                                                            \
        }                                                                      \
      }                                                                        \
      int g = min(ld, rd);                                                     \
      col2[y][xx] = (float)(g * g);                                            \
    }                                                                          \
  }                                                                            \
  __syncthreads();                                                             \
  _Pragma("unroll")                                                            \
  for (int j = 0; j < 8; ++j) {                                                \
    int y = yg * 8 + j;                                                        \
    float best = col2[y][xq];                                                  \
    for (int k = 1; k < H; ++k) {                                              \
      float k2 = (float)(k * k);                                               \
      if (k2 >= best) break;           /* no farther candidate improves */     \
      int ym = y - k, yd = y + k;                                              \
      if (ym >= 0) best = fminf(best, col2[ym][xq] + k2);                      \
      if (yd < H)  best = fminf(best, col2[yd][xq] + k2);                      \
    }                                                                          \
    (DIST)[j] = sqrtf(best);                                                   \
  }                                                                            \
  __syncthreads();

// ---------------------------------------------------------------------------
// K2: fused morpho+rmm+final — the r11/r13-proven champion structure:
// padded counters + padded rmm/sums, relaxed+threadfence tail.
// ---------------------------------------------------------------------------
__global__ void __launch_bounds__(256, 1) fused_kernel(
    const float* __restrict__ y_pred, const u64* __restrict__ mask_bits,
    u64* __restrict__ skel_bits, unsigned* __restrict__ rmm_u,
    double* __restrict__ sums, unsigned* __restrict__ cnts,
    float* __restrict__ out) {
  __shared__ u64 SA[H][WPR];
  __shared__ u64 SB[H][WPR];
  __shared__ float col2[H][XT + 1];
  __shared__ u64 srow_t[H];
  __shared__ u64 srow_p[H];
  __shared__ u64 msk_row[H];
  __shared__ float redf[4][4];
  __shared__ unsigned smm[4];
  int t = threadIdx.x;

  if (blockIdx.x < NSKEL) {
    // --- soft_skel, bit-packed, 1 thread per row, ONE barrier per level ---
    int bi = blockIdx.x;                  // branch*4+img
    int y = t;
    int base = bi * WPI;
    u64 a[WPR], cur[WPR], e[WPR], d[WPR], sk[WPR];
#pragma unroll
    for (int k = 0; k < WPR; ++k) { a[k] = mask_bits[base + y*WPR + k]; SA[y][k] = a[k]; }
    __syncthreads();
    erode_from(SA, y, e);                 // E1 = erode(a)
#pragma unroll
    for (int k = 0; k < WPR; ++k) SB[y][k] = e[k];
    __syncthreads();                      // SB visible; all SA reads complete
    dilate_from(SB, y, d);                // open(a)
#pragma unroll
    for (int k = 0; k < WPR; ++k) { sk[k] = a[k] & ~d[k]; cur[k] = e[k]; }
    u64 (*P)[WPR] = SB;                   // current erosion level E_k
    u64 (*Q)[WPR] = SA;                   // dead buffer
    for (int it = 0; it < 10; ++it) {     // levels 1..10
      erode_from(P, y, e);                // E_{k+1}
#pragma unroll
      for (int k = 0; k < WPR; ++k) Q[y][k] = e[k];   // overwrite dead data
      __syncthreads();                    // publish Q; P reads all done
      dilate_from(Q, y, d);               // open(E_k)
#pragma unroll
      for (int k = 0; k < WPR; ++k) { sk[k] |= cur[k] & ~d[k]; cur[k] = e[k]; }
      u64 (*T)[WPR] = P; P = Q; Q = T;
    }
#pragma unroll
    for (int k = 0; k < WPR; ++k) skel_bits[base + y*WPR + k] = sk[k];
    __syncthreads();                      // all stores issued + vmcnt drained
    if (t == 0) {
      __threadfence();                    // release: writeback this XCD's L2 (8 total)
      atomicAdd(&cnts[CFLAG(bi)], 1u);    // per-(branch,image) flag, own line
    }
    return;
  }

  // ===================== tile blocks (8..135) =====================
  int tb  = blockIdx.x - NSKEL;          // 0..127
  int img = tb >> 5;                     // 0..3
  int xt  = tb & 31;                     // 0..31
  int x0  = xt * XT;
  int kx  = x0 >> 6;                     // tile's 8 columns share this word
  int sh0 = x0 & 63;                     // <= 56
  int xq  = t & (XT - 1);                // phase-2/q column 0..7
  int yg  = t >> 3;                      // phase-2/q row group 0..31

  float dist_t[8], dist_p[8];
  EDT_PASS(mask_bits + img*WPI,       dist_t, 1)   // true branch (saves mask word)
  EDT_PASS(mask_bits + (4+img)*WPI,   dist_p, 0)   // pred branch

  // --- wait for BOTH skel flags: ONE combined poll loop, own lines ---
  if (t == 0) {
    while (__hip_atomic_load(&cnts[CFLAG(img)], __ATOMIC_RELAXED,
                             __HIP_MEMORY_SCOPE_AGENT) == 0u ||
           __hip_atomic_load(&cnts[CFLAG(4+img)], __ATOMIC_RELAXED,
                             __HIP_MEMORY_SCOPE_AGENT) == 0u)
      __builtin_amdgcn_s_sleep(8);
  }
  __syncthreads();
  // stage skel words for this tile (sc1: bypass stale L2, LLC-coherent —
  // fine HERE: 2 loads/thread once, NOT in a hot loop (r14 lesson))
  srow_t[t] = __hip_atomic_load(&skel_bits[img*WPI + t*WPR + kx],
                                __ATOMIC_RELAXED, __HIP_MEMORY_SCOPE_AGENT);
  srow_p[t] = __hip_atomic_load(&skel_bits[(4+img)*WPI + t*WPR + kx],
                                __ATOMIC_RELAXED, __HIP_MEMORY_SCOPE_AGENT);
  __syncthreads();

  // --- fused rmax/rmin for BOTH branches (regs + LDS only) ---
  float vmax_t = 0.0f, vmin_t = 3.0e38f, vmax_p = 0.0f, vmin_p = 3.0e38f;
#pragma unroll
  for (int j = 0; j < 8; ++j) {
    int y = yg * 8 + j;
    int sb_t = (int)((srow_t[y] >> (sh0 + xq)) & 1ULL);
    int sb_p = (int)((srow_p[y] >> (sh0 + xq)) & 1ULL);
    float srt = sb_t ? dist_t[j] : 0.0f;  // skel_radius, true branch
    float srp = sb_p ? dist_p[j] : 0.0f;  // skel_radius, pred branch
    vmax_t = fmaxf(vmax_t, srt); vmin_t = fminf(vmin_t, srt);
    vmax_p = fmaxf(vmax_p, srp); vmin_p = fminf(vmin_p, srp);
  }
  for (int o = 32; o > 0; o >>= 1) {
    vmax_t = fmaxf(vmax_t, __shfl_down(vmax_t, o, 64));
    vmin_t = fminf(vmin_t, __shfl_down(vmin_t, o, 64));
    vmax_p = fmaxf(vmax_p, __shfl_down(vmax_p, o, 64));
    vmin_p = fminf(vmin_p, __shfl_down(vmin_p, o, 64));
  }
  int wave = t >> 6, lane = t & 63;
  if (lane == 0) { redf[wave][0]=vmax_t; redf[wave][1]=vmin_t;
                   redf[wave][2]=vmax_p; redf[wave][3]=vmin_p; }
  __syncthreads();
  if (t == 0) {
    float mxt=redf[0][0], mnt=redf[0][1], mxp=redf[0][2], mnp=redf[0][3];
    for (int wv = 1; wv < 4; ++wv) {
      mxt = fmaxf(mxt, redf[wv][0]); mnt = fminf(mnt, redf[wv][1]);
      mxp = fmaxf(mxp, redf[wv][2]); mnp = fminf(mnp, redf[wv][3]);
    }
    // padded rmm: each entry on its own 128-B line -> 32 RMWs/line, parallel
    atomicMax(&rmm_u[RMM(img*2 + 0)], __float_as_uint(mxt));
    atomicMin(&rmm_u[RMM(img*2 + 1)], __float_as_uint(mnt));
    atomicMax(&rmm_u[RMM((4+img)*2 + 0)], __float_as_uint(mxp));
    atomicMin(&rmm_u[RMM((4+img)*2 + 1)], __float_as_uint(mnp));
    // per-image sub-barrier (32 arrivals), own 128-B line: release RMW
    // orders the rmm atomics (all at LLC — nothing dirty in L2)
    __hip_atomic_fetch_add(&cnts[CBAR(img)], 1u, __ATOMIC_RELEASE,
                           __HIP_MEMORY_SCOPE_AGENT);
    while (__hip_atomic_load(&cnts[CBAR(img)], __ATOMIC_RELAXED,
                             __HIP_MEMORY_SCOPE_AGENT) < 32u)
      __builtin_amdgcn_s_sleep(8);
  }
  __syncthreads();
  if (t < 4) {
    int idx = (t < 2) ? (img*2 + t) : ((4+img)*2 + (t-2));
    smm[t] = __hip_atomic_load(&rmm_u[RMM(idx)], __ATOMIC_RELAXED,
                               __HIP_MEMORY_SCOPE_AGENT);
  }
  __syncthreads();
  float rmax_t = fmaxf(__uint_as_float(smm[0]), 1.0f);
  float rmin_t = fmaxf(__uint_as_float(smm[1]), 1.0f);
  float rmax_p = fmaxf(__uint_as_float(smm[2]), 1.0f);
  float rmin_p = fmaxf(__uint_as_float(smm[3]), 1.0f);

  // --- q-phase over this block's OWN 2048 pixels (dist in regs) ---
  float q1 = 0.f, q2 = 0.f, q3 = 0.f, q4 = 0.f;
#pragma unroll
  for (int j = 0; j < 8; ++j) {
    int y = yg * 8 + j;
    float xv = y_pred[img*NPIX + y*W + x0 + xq];
    float p = 1.0f / (1.0f + expf(-xv));
    float ppv = 1.0f / (1.0f + expf(-(2.0f * p - 1.0f)));  // exact ref expr
    int b = sh0 + xq;
    int m_t  = (int)((msk_row[y] >> b) & 1ULL);
    int s_t  = (int)((srow_t[y] >> b) & 1ULL);
    int s_pb = (int)((srow_p[y] >> b) & 1ULL);
    // --- true branch (binary) ---
    float distances_t = m_t ? dist_t[j] : 0.0f;
    float skelrad_t   = s_t ? distances_t : 0.0f;
    float dmn_t = fminf(distances_t, rmax_t) / rmax_t;
    float srn_t = skelrad_t / rmax_t;
    float In_t  = s_t ? (rmax_t - skelrad_t + rmin_t) / rmax_t : 0.0f;
    float q_vl   = m_t ? dmn_t : 0.0f;
    float q_slvl = m_t ? srn_t : 0.0f;
    float q_sl   = s_t ? In_t  : 0.0f;
    // --- pred branch (probabilistic) ---
    float skel_in_p = s_pb ? ppv : 0.0f;      // skel_pred_prob
    bool msk_p = ppv > 0.5f;
    bool sk_p  = skel_in_p > 0.5f;
    float distances_p = msk_p ? dist_p[j] : 0.0f;
    float skelrad_p   = sk_p ? distances_p : 0.0f;
    float dmn_p = fminf(distances_p, rmax_p) / rmax_p;
    float srn_p = skelrad_p / rmax_p;
    float In_p  = sk_p ? (rmax_p - skelrad_p + rmin_p) / rmax_p : 0.0f;
    float q_vp   = dmn_p * ppv;
    float q_spvp = srn_p * ppv;
    float q_sp   = In_p * skel_in_p;
    q1 += q_sp * q_vl;
    q2 += (q_spvp != 0.0f && q_slvl == 0.0f) ? q_spvp * q_sp : q_slvl * q_sp;
    q3 += q_sl * q_vp;
    q4 += (q_slvl != 0.0f && q_spvp == 0.0f) ? q_slvl * q_sl : q_spvp * q_sl;
  }
  for (int o = 32; o > 0; o >>= 1) {
    q1 += __shfl_down(q1, o, 64);
    q2 += __shfl_down(q2, o, 64);
    q3 += __shfl_down(q3, o, 64);
    q4 += __shfl_down(q4, o, 64);
  }
  if (lane == 0) { redf[wave][0]=q1; redf[wave][1]=q2; redf[wave][2]=q3; redf[wave][3]=q4; }
  __syncthreads();
  if (t == 0) {
    float a0=0,a1=0,a2=0,a3=0;
    for (int wv = 0; wv < 4; ++wv) {
      a0 += redf[wv][0]; a1 += redf[wv][1]; a2 += redf[wv][2]; a3 += redf[wv][3];
    }
    // padded sums: one double per 128-B line -> 128 RMWs/line, 4 lines parallel
    atomicAdd(&sums[SUM(0)], (double)a0);
    atomicAdd(&sums[SUM(1)], (double)a1);
    atomicAdd(&sums[SUM(2)], (double)a2);
    atomicAdd(&sums[SUM(3)], (double)a3);
    __threadfence();                    // release-only: writeback, NO invalidate
    unsigned c = atomicAdd(&cnts[CDONE], 1u);
    if (c == NTILE - 1) {               // last block finalizes (device-scope
      double s0 = atomicAdd(&sums[SUM(0)], 0.0);  // atomic loads for coherence)
      double s1 = atomicAdd(&sums[SUM(1)], 0.0);
      double s2 = atomicAdd(&sums[SUM(2)], 0.0);
      double s3 = atomicAdd(&sums[SUM(3)], 0.0);
      double wp  = (s0 + 1.0) / (s1 + 1.0);
      double wsn = (s2 + 1.0) / (s3 + 1.0);
      out[0] = (float)(1.0 - 2.0 * (wp * wsn) / (wp + wsn));
    }
  }
}

extern "C" void kernel_launch(void* const* d_in, const int* in_sizes, int n_in,
                              void* d_out, int out_size, void* d_ws, size_t ws_size,
                              hipStream_t stream) {
  (void)in_sizes; (void)n_in; (void)out_size; (void)ws_size;
  const float* y_pred = (const float*)d_in[0];
  const int*   y_true = (const int*)d_in[1];
  float* out = (float*)d_out;
  char* ws = (char*)d_ws;

  // workspace layout (bytes) — ALL hot atomics on private 128-B lines
  u64*   mask_bits = (u64*)  (ws + 0);          // 8192 u64 (65,536 B)
  u64*   skel_bits = (u64*)  (ws + 65536);      // 8192 u64 (65,536 B)
  unsigned* rmm_u  = (unsigned*)(ws + 131072);  // 16 entries x 128 B (2048 B)
  double* sums     = (double*)(ws + 133120);    // 4 entries x 128 B (512 B)
  unsigned* cnts   = (unsigned*)(ws + 133632);  // 512 u32, 1 counter/128 B

  prep_kernel<<<NTOT/256, 256, 0, stream>>>(y_pred, y_true, mask_bits, rmm_u, sums, cnts);
  fused_kernel<<<NB2, 256, 0, stream>>>(y_pred, mask_bits, skel_bits, rmm_u, sums, cnts, out);
}